// Round 5
// baseline (56.376 us; speedup 1.0000x reference)
//
#include <hip/hip_runtime.h>

// StatefulFormantFilter: B=32, T=48000, F=5
// y[t] = x[t] + 2 r cos(th) y[t-1] - r^2 y[t-2],  r=exp(-pi bw/SR), th=2 pi cf/SR
// x = excitation * (1-r^2) sin(th);  out = sum_f y;  new_states = (y[T-1], y[T-2])
//
// No stored chunk maps (recompute > store: min traffic = inputs + out).
// K1: block=(b, 64-chunk group)x5f: compute chunk maps (f-fastest coalesced
//     loads), LDS exchange, wave-per-formant scan -> ONLY 8-float group
//     product to Gprod (240 KB). No Aws.
// K2: per chain: wave-scan over NG=47 group products -> group-entering
//     states Sg + final new_states.
// K3: recompute maps (L3-warm inputs), redo block scan -> exclusive map per
//     chunk, entering state = map(Sg), replay 16 steps, f-sum via padded
//     LDS, coalesced float stores.

constexpr int B = 32;
constexpr int T = 48000;
constexpr int F = 5;
constexpr int L = 16;          // chunk length
constexpr int C = T / L;       // 3000 chunks per chain
constexpr int GS = 64;         // chunks per group (one wave per formant)
constexpr int NG = (C + GS - 1) / GS;  // 47 groups
constexpr int NCHAIN = B * F;  // 160
constexpr int THREADS = GS * F;        // 320 = 5 waves
constexpr int MROW = GS * 6 + 5;       // padded LDS map row (break f-bank-align)

#define CBW2 (-9.4416635e-05f)   // -pi/(48000*ln2)
#define CCF  (1.3089969e-04f)    // 2*pi/48000

// Compute the affine chunk map for chunk c of chain (b,f):
// columns u=(resp to (1,0)), v=(resp to (0,1)), w=driven offset.
__device__ __forceinline__ void chunk_map(
    const float* __restrict__ exc, const float* __restrict__ cf,
    const float* __restrict__ bw, int b, int c, int f,
    float& u1, float& u2, float& v1, float& v2, float& w1, float& w2) {
  int t0 = c * L;
  const float* cfp = cf + (size_t)(b * T + t0) * F + f;
  const float* bwp = bw + (size_t)(b * T + t0) * F + f;
  const float* ep  = exc + (size_t)b * T + t0;
  #pragma unroll
  for (int i = 0; i < L; ++i) {
    float bwf = bwp[(size_t)i * F];
    float cff = cfp[(size_t)i * F];
    float e   = ep[i];
    float r  = exp2f(CBW2 * bwf);
    float th = CCF * cff;
    float sn = __sinf(th);
    float cs = __cosf(th);
    float p = 2.f * r * cs;     // -a1
    float q = -r * r;           // -a2
    float g = fmaf(q, sn, sn);  // (1-r^2) sin(th)
    float x = e * g;
    float nu = fmaf(p, u1, q * u2);
    float nv = fmaf(p, v1, q * v2);
    float nw = fmaf(p, w1, fmaf(q, w2, x));
    u2 = u1; u1 = nu;
    v2 = v1; v1 = nv;
    w2 = w1; w1 = nw;
  }
}

// Inclusive Hillis-Steele scan of affine maps across a wave (newest-on-left).
__device__ __forceinline__ void wave_scan_maps(int lane, float& u1, float& u2,
                                               float& v1, float& v2,
                                               float& w1, float& w2) {
  #pragma unroll
  for (int d = 1; d < 64; d <<= 1) {
    float pu1 = __shfl_up(u1, d);
    float pv1 = __shfl_up(v1, d);
    float pu2 = __shfl_up(u2, d);
    float pv2 = __shfl_up(v2, d);
    float pw1 = __shfl_up(w1, d);
    float pw2 = __shfl_up(w2, d);
    bool has = (lane >= d);
    pu1 = has ? pu1 : 1.f;  pv1 = has ? pv1 : 0.f;
    pu2 = has ? pu2 : 0.f;  pv2 = has ? pv2 : 1.f;
    pw1 = has ? pw1 : 0.f;  pw2 = has ? pw2 : 0.f;
    float nu1 = fmaf(u1, pu1, v1 * pu2);
    float nv1 = fmaf(u1, pv1, v1 * pv2);
    float nu2 = fmaf(u2, pu1, v2 * pu2);
    float nv2 = fmaf(u2, pv1, v2 * pv2);
    float nw1 = fmaf(u1, pw1, fmaf(v1, pw2, w1));
    float nw2 = fmaf(u2, pw1, fmaf(v2, pw2, w2));
    u1 = nu1; v1 = nv1; u2 = nu2; v2 = nv2; w1 = nw1; w2 = nw2;
  }
}

__global__ __launch_bounds__(THREADS) void k1_kernel(
    const float* __restrict__ exc, const float* __restrict__ cf,
    const float* __restrict__ bw, float* __restrict__ Gprod) {
  __shared__ float smaps[F][MROW];

  int bg = blockIdx.x;
  int b = bg / NG;
  int g = bg % NG;
  int tid = threadIdx.x;
  int c_local = tid / F;
  int f = tid % F;
  int c = g * GS + c_local;

  float u1 = 1.f, u2 = 0.f, v1 = 0.f, v2 = 1.f, w1 = 0.f, w2 = 0.f;
  if (c < C) chunk_map(exc, cf, bw, b, c, f, u1, u2, v1, v2, w1, w2);

  float* m = &smaps[f][c_local * 6];
  m[0] = u1; m[1] = u2; m[2] = v1; m[3] = v2; m[4] = w1; m[5] = w2;
  __syncthreads();

  int w = tid >> 6;       // wave id == formant id (0..4)
  int lane = tid & 63;    // lane == chunk within group
  const float* s = &smaps[w][lane * 6];
  float a1 = s[0], a2 = s[1], a3 = s[2], a4 = s[3], a5 = s[4], a6 = s[5];
  wave_scan_maps(lane, a1, a2, a3, a4, a5, a6);

  if (lane == 63) {
    int chain = b * F + w;
    float4* gp = (float4*)(Gprod + (size_t)(chain * NG + g) * 8);
    gp[0] = make_float4(a1, a2, a3, a4);
    gp[1] = make_float4(a5, a6, 0.f, 0.f);
  }
}

__global__ __launch_bounds__(64) void k2_kernel(
    const float* __restrict__ Gprod, const float* __restrict__ states0,
    float* __restrict__ Sg, float* __restrict__ out_states) {
  int chain = blockIdx.x;
  int lane = threadIdx.x;

  float u1 = 1.f, u2 = 0.f, v1 = 0.f, v2 = 1.f, w1 = 0.f, w2 = 0.f;
  if (lane < NG) {
    const float4* gp = (const float4*)(Gprod + (size_t)(chain * NG + lane) * 8);
    float4 A0 = gp[0];
    float4 A1 = gp[1];
    u1 = A0.x; u2 = A0.y; v1 = A0.z; v2 = A0.w; w1 = A1.x; w2 = A1.y;
  }

  wave_scan_maps(lane, u1, u2, v1, v2, w1, w2);

  float s01 = states0[chain * 2 + 0];
  float s02 = states0[chain * 2 + 1];

  // exclusive prefix -> state entering group g
  float eu1 = __shfl_up(u1, 1), ev1 = __shfl_up(v1, 1);
  float eu2 = __shfl_up(u2, 1), ev2 = __shfl_up(v2, 1);
  float ew1 = __shfl_up(w1, 1), ew2 = __shfl_up(w2, 1);
  if (lane == 0) { eu1 = 1.f; ev1 = 0.f; eu2 = 0.f; ev2 = 1.f; ew1 = 0.f; ew2 = 0.f; }
  if (lane < NG) {
    float sy1 = fmaf(eu1, s01, fmaf(ev1, s02, ew1));
    float sy2 = fmaf(eu2, s01, fmaf(ev2, s02, ew2));
    *(float2*)(Sg + (size_t)(chain * NG + lane) * 2) = make_float2(sy1, sy2);
  }

  // final state (identity pads make lane63 the full product)
  float ay1 = fmaf(u1, s01, fmaf(v1, s02, w1));
  float ay2 = fmaf(u2, s01, fmaf(v2, s02, w2));
  float fy1 = __shfl(ay1, 63);
  float fy2 = __shfl(ay2, 63);
  if (lane == 0) {
    out_states[chain * 2 + 0] = fy1;
    out_states[chain * 2 + 1] = fy2;
  }
}

constexpr int P3_ROW = GS * (L + 1);   // +1 pad per chunk: conflict-free

__global__ __launch_bounds__(THREADS) void k3_kernel(
    const float* __restrict__ exc, const float* __restrict__ cf,
    const float* __restrict__ bw, const float* __restrict__ Sg,
    float* __restrict__ out) {
  __shared__ float smaps[F][MROW];
  __shared__ float red[F][P3_ROW];

  int bg = blockIdx.x;
  int b = bg / NG;
  int g = bg % NG;
  int c0 = g * GS;
  int nc = (C - c0 < GS) ? (C - c0) : GS;
  int tid = threadIdx.x;
  int c_local = tid / F;
  int f = tid % F;
  int c = c0 + c_local;

  // phase A: recompute chunk maps
  float u1 = 1.f, u2 = 0.f, v1 = 0.f, v2 = 1.f, w1 = 0.f, w2 = 0.f;
  if (c < C) chunk_map(exc, cf, bw, b, c, f, u1, u2, v1, v2, w1, w2);
  {
    float* m = &smaps[f][c_local * 6];
    m[0] = u1; m[1] = u2; m[2] = v1; m[3] = v2; m[4] = w1; m[5] = w2;
  }
  __syncthreads();

  // phase B: wave-per-formant scan, write EXCLUSIVE maps back
  {
    int w = tid >> 6;
    int lane = tid & 63;
    const float* s = &smaps[w][lane * 6];
    float a1 = s[0], a2 = s[1], a3 = s[2], a4 = s[3], a5 = s[4], a6 = s[5];
    wave_scan_maps(lane, a1, a2, a3, a4, a5, a6);
    float e1 = __shfl_up(a1, 1), e2 = __shfl_up(a2, 1);
    float e3 = __shfl_up(a3, 1), e4 = __shfl_up(a4, 1);
    float e5 = __shfl_up(a5, 1), e6 = __shfl_up(a6, 1);
    if (lane == 0) { e1 = 1.f; e2 = 0.f; e3 = 0.f; e4 = 1.f; e5 = 0.f; e6 = 0.f; }
    __syncthreads();   // everyone done reading inclusive inputs
    float* d = &smaps[w][lane * 6];
    d[0] = e1; d[1] = e2; d[2] = e3; d[3] = e4; d[4] = e5; d[5] = e6;
  }
  __syncthreads();

  // phase C/D: entering state + replay
  if (c_local < nc) {
    const float* m = &smaps[f][c_local * 6];
    float x1 = m[0], x2 = m[1], x3 = m[2], x4 = m[3], x5 = m[4], x6 = m[5];
    int chain = b * F + f;
    float2 sg = *(const float2*)(Sg + (size_t)(chain * NG + g) * 2);
    float y1 = fmaf(x1, sg.x, fmaf(x3, sg.y, x5));
    float y2 = fmaf(x2, sg.x, fmaf(x4, sg.y, x6));

    int t0 = c * L;
    const float* cfp = cf + (size_t)(b * T + t0) * F + f;
    const float* bwp = bw + (size_t)(b * T + t0) * F + f;
    const float* ep  = exc + (size_t)b * T + t0;

    #pragma unroll
    for (int i = 0; i < L; ++i) {
      float bwf = bwp[(size_t)i * F];
      float cff = cfp[(size_t)i * F];
      float e   = ep[i];
      float r  = exp2f(CBW2 * bwf);
      float th = CCF * cff;
      float sn = __sinf(th);
      float cs = __cosf(th);
      float p = 2.f * r * cs;
      float q = -r * r;
      float gn = fmaf(q, sn, sn);
      float x = e * gn;
      float y = fmaf(p, y1, fmaf(q, y2, x));
      red[f][c_local * (L + 1) + i] = y;
      y2 = y1;
      y1 = y;
    }
  }
  __syncthreads();

  // f-sum reduction, coalesced store
  int nt = nc * L;
  int tbase = b * T + c0 * L;
  for (int t = tid; t < nt; t += THREADS) {
    int ci = t >> 4;
    int ii = t & (L - 1);
    int a = ci * (L + 1) + ii;
    float s = red[0][a] + red[1][a] + red[2][a] + red[3][a] + red[4][a];
    out[tbase + t] = s;
  }
}

extern "C" void kernel_launch(void* const* d_in, const int* in_sizes, int n_in,
                              void* d_out, int out_size, void* d_ws, size_t ws_size,
                              hipStream_t stream) {
  const float* exc = (const float*)d_in[0];   // (B,T,1)
  const float* cf  = (const float*)d_in[1];   // (B,T,F)
  const float* bw  = (const float*)d_in[2];   // (B,T,F)
  const float* st  = (const float*)d_in[3];   // (B,F,2)
  float* out        = (float*)d_out;          // (B,T,1) then (B,F,2)
  float* out_states = out + (size_t)B * T;

  float* Gprod = (float*)d_ws;                       // NCHAIN*NG*8 floats = 240 KB
  float* Sg    = Gprod + (size_t)NCHAIN * NG * 8;    // NCHAIN*NG*2 floats = 60 KB

  k1_kernel<<<B * NG, THREADS, 0, stream>>>(exc, cf, bw, Gprod);
  k2_kernel<<<NCHAIN, 64, 0, stream>>>(Gprod, st, Sg, out_states);
  k3_kernel<<<B * NG, THREADS, 0, stream>>>(exc, cf, bw, Sg, out);
}

// Round 6
// 44.628 us; speedup vs baseline: 1.2632x; 1.2632x over previous
//
#include <hip/hip_runtime.h>

// StatefulFormantFilter: B=32, T=48000, F=5
// y[t] = x[t] + 2 r cos(th) y[t-1] - r^2 y[t-2],  r=exp(-pi bw/SR), th=2 pi cf/SR
// x = excitation * (1-r^2) sin(th);  out = sum_f y;  new_states = (y[T-1], y[T-2])
//
// R6 structure (R4 dataflow + pass2a fused into pass1):
// K1: block=(b, 64-chunk group)x5f: build chunk maps, LDS exchange,
//     wave-per-formant inclusive scan -> scanned maps to Aws (cache-resident
//     15.4 MB) + 8-float group product to Gprod.
// K2: per chain: wave-scan over NG=47 group products -> group-entering
//     states Sg + final new_states.
// K3: per (b,chunk,f): entering state = Aws[c-1] applied to Sg[g]; replay 16
//     steps, f-sum via padded LDS, coalesced stores. (== R4 pass3)

constexpr int B = 32;
constexpr int T = 48000;
constexpr int F = 5;
constexpr int L = 16;          // chunk length
constexpr int C = T / L;       // 3000 chunks per chain
constexpr int GS = 64;         // chunks per group (one wave per formant)
constexpr int NG = (C + GS - 1) / GS;  // 47 groups
constexpr int NCHAIN = B * F;  // 160
constexpr int THREADS = GS * F;        // 320 = 5 waves
constexpr int MSTRIDE = 7;             // LDS map stride (7 coprime 32: no conflicts)
constexpr int MROW = GS * MSTRIDE;     // 448 floats per formant row

#define CBW2 (-9.4416635e-05f)   // -pi/(48000*ln2)
#define CCF  (1.3089969e-04f)    // 2*pi/48000

__device__ __forceinline__ float fast_exp2(float x) {
#if __has_builtin(__builtin_amdgcn_exp2f)
  return __builtin_amdgcn_exp2f(x);
#else
  return exp2f(x);
#endif
}

// Compute the affine chunk map for chunk c of chain (b,f):
// columns u=(resp to (1,0)), v=(resp to (0,1)), w=driven offset.
__device__ __forceinline__ void chunk_map(
    const float* __restrict__ exc, const float* __restrict__ cf,
    const float* __restrict__ bw, int b, int c, int f,
    float& u1, float& u2, float& v1, float& v2, float& w1, float& w2) {
  int t0 = c * L;
  const float* cfp = cf + (size_t)(b * T + t0) * F + f;
  const float* bwp = bw + (size_t)(b * T + t0) * F + f;
  const float* ep  = exc + (size_t)b * T + t0;
  #pragma unroll
  for (int i = 0; i < L; ++i) {
    float bwf = bwp[(size_t)i * F];
    float cff = cfp[(size_t)i * F];
    float e   = ep[i];
    float r  = fast_exp2(CBW2 * bwf);
    float th = CCF * cff;
    float sn = __sinf(th);
    float cs = __cosf(th);
    float p = 2.f * r * cs;     // -a1
    float q = -r * r;           // -a2
    float g = fmaf(q, sn, sn);  // (1-r^2) sin(th)
    float x = e * g;
    float nu = fmaf(p, u1, q * u2);
    float nv = fmaf(p, v1, q * v2);
    float nw = fmaf(p, w1, fmaf(q, w2, x));
    u2 = u1; u1 = nu;
    v2 = v1; v1 = nv;
    w2 = w1; w1 = nw;
  }
}

// Inclusive Hillis-Steele scan of affine maps across a wave (newest-on-left).
__device__ __forceinline__ void wave_scan_maps(int lane, float& u1, float& u2,
                                               float& v1, float& v2,
                                               float& w1, float& w2) {
  #pragma unroll
  for (int d = 1; d < 64; d <<= 1) {
    float pu1 = __shfl_up(u1, d);
    float pv1 = __shfl_up(v1, d);
    float pu2 = __shfl_up(u2, d);
    float pv2 = __shfl_up(v2, d);
    float pw1 = __shfl_up(w1, d);
    float pw2 = __shfl_up(w2, d);
    bool has = (lane >= d);
    pu1 = has ? pu1 : 1.f;  pv1 = has ? pv1 : 0.f;
    pu2 = has ? pu2 : 0.f;  pv2 = has ? pv2 : 1.f;
    pw1 = has ? pw1 : 0.f;  pw2 = has ? pw2 : 0.f;
    float nu1 = fmaf(u1, pu1, v1 * pu2);
    float nv1 = fmaf(u1, pv1, v1 * pv2);
    float nu2 = fmaf(u2, pu1, v2 * pu2);
    float nv2 = fmaf(u2, pv1, v2 * pv2);
    float nw1 = fmaf(u1, pw1, fmaf(v1, pw2, w1));
    float nw2 = fmaf(u2, pw1, fmaf(v2, pw2, w2));
    u1 = nu1; v1 = nv1; u2 = nu2; v2 = nv2; w1 = nw1; w2 = nw2;
  }
}

__global__ __launch_bounds__(THREADS) void k1_kernel(
    const float* __restrict__ exc, const float* __restrict__ cf,
    const float* __restrict__ bw, float* __restrict__ Aws,
    float* __restrict__ Gprod) {
  __shared__ float smaps[F][MROW];

  int bg = blockIdx.x;
  int b = bg / NG;
  int g = bg % NG;
  int tid = threadIdx.x;
  int c_local = tid / F;
  int f = tid % F;
  int c = g * GS + c_local;

  float u1 = 1.f, u2 = 0.f, v1 = 0.f, v2 = 1.f, w1 = 0.f, w2 = 0.f;
  if (c < C) chunk_map(exc, cf, bw, b, c, f, u1, u2, v1, v2, w1, w2);

  float* m = &smaps[f][c_local * MSTRIDE];
  m[0] = u1; m[1] = u2; m[2] = v1; m[3] = v2; m[4] = w1; m[5] = w2;
  __syncthreads();

  int w = tid >> 6;       // wave id == formant id (0..4)
  int lane = tid & 63;    // lane == chunk within group
  const float* s = &smaps[w][lane * MSTRIDE];
  float a1 = s[0], a2 = s[1], a3 = s[2], a4 = s[3], a5 = s[4], a6 = s[5];
  wave_scan_maps(lane, a1, a2, a3, a4, a5, a6);

  int c2 = g * GS + lane;
  int chain = b * F + w;
  if (c2 < C) {
    float4* o = (float4*)(Aws + ((size_t)chain * C + c2) * 8);
    o[0] = make_float4(a1, a2, a3, a4);
    o[1] = make_float4(a5, a6, 0.f, 0.f);
  }
  if (lane == 63) {
    float4* gp = (float4*)(Gprod + (size_t)(chain * NG + g) * 8);
    gp[0] = make_float4(a1, a2, a3, a4);
    gp[1] = make_float4(a5, a6, 0.f, 0.f);
  }
}

__global__ __launch_bounds__(64) void k2_kernel(
    const float* __restrict__ Gprod, const float* __restrict__ states0,
    float* __restrict__ Sg, float* __restrict__ out_states) {
  int chain = blockIdx.x;
  int lane = threadIdx.x;

  float u1 = 1.f, u2 = 0.f, v1 = 0.f, v2 = 1.f, w1 = 0.f, w2 = 0.f;
  if (lane < NG) {
    const float4* gp = (const float4*)(Gprod + (size_t)(chain * NG + lane) * 8);
    float4 A0 = gp[0];
    float4 A1 = gp[1];
    u1 = A0.x; u2 = A0.y; v1 = A0.z; v2 = A0.w; w1 = A1.x; w2 = A1.y;
  }

  wave_scan_maps(lane, u1, u2, v1, v2, w1, w2);

  float s01 = states0[chain * 2 + 0];
  float s02 = states0[chain * 2 + 1];

  // exclusive prefix -> state entering group g
  float eu1 = __shfl_up(u1, 1), ev1 = __shfl_up(v1, 1);
  float eu2 = __shfl_up(u2, 1), ev2 = __shfl_up(v2, 1);
  float ew1 = __shfl_up(w1, 1), ew2 = __shfl_up(w2, 1);
  if (lane == 0) { eu1 = 1.f; ev1 = 0.f; eu2 = 0.f; ev2 = 1.f; ew1 = 0.f; ew2 = 0.f; }
  if (lane < NG) {
    float sy1 = fmaf(eu1, s01, fmaf(ev1, s02, ew1));
    float sy2 = fmaf(eu2, s01, fmaf(ev2, s02, ew2));
    *(float2*)(Sg + (size_t)(chain * NG + lane) * 2) = make_float2(sy1, sy2);
  }

  // final state (identity pads make lane63 the full product)
  float ay1 = fmaf(u1, s01, fmaf(v1, s02, w1));
  float ay2 = fmaf(u2, s01, fmaf(v2, s02, w2));
  float fy1 = __shfl(ay1, 63);
  float fy2 = __shfl(ay2, 63);
  if (lane == 0) {
    out_states[chain * 2 + 0] = fy1;
    out_states[chain * 2 + 1] = fy2;
  }
}

constexpr int P3_ROW = GS * (L + 1);   // +1 pad per chunk: conflict-free

__global__ __launch_bounds__(THREADS) void k3_kernel(
    const float* __restrict__ exc, const float* __restrict__ cf,
    const float* __restrict__ bw, const float* __restrict__ Aws,
    const float* __restrict__ Sg, float* __restrict__ out) {
  __shared__ float red[F][P3_ROW];

  int bg = blockIdx.x;
  int b = bg / NG;
  int g = bg % NG;
  int c0 = g * GS;
  int nc = (C - c0 < GS) ? (C - c0) : GS;

  int tid = threadIdx.x;
  int c_local = tid / F;
  int f = tid % F;

  if (c_local < nc) {
    int c = c0 + c_local;
    int chain = b * F + f;

    // entering state of chunk c (Aws holds group-local inclusive maps)
    float2 sg = *(const float2*)(Sg + (size_t)(chain * NG + g) * 2);
    float y1, y2;
    if (c_local == 0) {
      y1 = sg.x;
      y2 = sg.y;
    } else {
      const float4* m = (const float4*)(Aws + ((size_t)chain * C + (c - 1)) * 8);
      float4 M0 = m[0];
      float4 M1 = m[1];
      y1 = fmaf(M0.x, sg.x, fmaf(M0.z, sg.y, M1.x));
      y2 = fmaf(M0.y, sg.x, fmaf(M0.w, sg.y, M1.y));
    }

    int t0 = c * L;
    const float* cfp = cf + (size_t)(b * T + t0) * F + f;
    const float* bwp = bw + (size_t)(b * T + t0) * F + f;
    const float* ep  = exc + (size_t)b * T + t0;

    #pragma unroll
    for (int i = 0; i < L; ++i) {
      float bwf = bwp[(size_t)i * F];
      float cff = cfp[(size_t)i * F];
      float e   = ep[i];
      float r  = fast_exp2(CBW2 * bwf);
      float th = CCF * cff;
      float sn = __sinf(th);
      float cs = __cosf(th);
      float p = 2.f * r * cs;
      float q = -r * r;
      float gn = fmaf(q, sn, sn);
      float x = e * gn;
      float y = fmaf(p, y1, fmaf(q, y2, x));
      red[f][c_local * (L + 1) + i] = y;
      y2 = y1;
      y1 = y;
    }
  }

  __syncthreads();

  int nt = nc * L;
  int tbase = b * T + c0 * L;
  for (int t = tid; t < nt; t += THREADS) {
    int ci = t >> 4;
    int ii = t & (L - 1);
    int a = ci * (L + 1) + ii;
    float s = red[0][a] + red[1][a] + red[2][a] + red[3][a] + red[4][a];
    out[tbase + t] = s;
  }
}

extern "C" void kernel_launch(void* const* d_in, const int* in_sizes, int n_in,
                              void* d_out, int out_size, void* d_ws, size_t ws_size,
                              hipStream_t stream) {
  const float* exc = (const float*)d_in[0];   // (B,T,1)
  const float* cf  = (const float*)d_in[1];   // (B,T,F)
  const float* bw  = (const float*)d_in[2];   // (B,T,F)
  const float* st  = (const float*)d_in[3];   // (B,F,2)
  float* out        = (float*)d_out;          // (B,T,1) then (B,F,2)
  float* out_states = out + (size_t)B * T;

  float* Aws   = (float*)d_ws;                       // NCHAIN*C*8 floats = 15.36 MB
  float* Gprod = Aws + (size_t)NCHAIN * C * 8;       // NCHAIN*NG*8 floats
  float* Sg    = Gprod + (size_t)NCHAIN * NG * 8;    // NCHAIN*NG*2 floats

  k1_kernel<<<B * NG, THREADS, 0, stream>>>(exc, cf, bw, Aws, Gprod);
  k2_kernel<<<NCHAIN, 64, 0, stream>>>(Gprod, st, Sg, out_states);
  k3_kernel<<<B * NG, THREADS, 0, stream>>>(exc, cf, bw, Aws, Sg, out);
}